// Round 4
// baseline (370.810 us; speedup 1.0000x reference)
//
#include <hip/hip_runtime.h>

#define NN 50000
#define NE 800000
#define D 128

#define HISTB 800       // 1024-thread blocks covering 800k edges
#define CVT_BLOCKS 1563 // ceil(1.6M / 1024)
#define WT_BLOCKS 48    // 3 matrices x 16384 / 1024
#define CSRCAP (NE + 4 * NN)

typedef short bf16x8 __attribute__((ext_vector_type(8)));
typedef float f32x4 __attribute__((ext_vector_type(4)));

// ---------------- bf16 helpers ----------------

__device__ __forceinline__ unsigned bf16rne(float f) {
  unsigned u = __float_as_uint(f);
  return (u + 0x7fffu + ((u >> 16) & 1u)) >> 16;
}
__device__ __forceinline__ unsigned packbf(float lo, float hi) {
  return bf16rne(lo) | (bf16rne(hi) << 16);
}
__device__ __forceinline__ void bacc(float* a, uint4 u) {
  a[0] += __uint_as_float(u.x << 16);
  a[1] += __uint_as_float(u.x & 0xffff0000u);
  a[2] += __uint_as_float(u.y << 16);
  a[3] += __uint_as_float(u.y & 0xffff0000u);
  a[4] += __uint_as_float(u.z << 16);
  a[5] += __uint_as_float(u.z & 0xffff0000u);
  a[6] += __uint_as_float(u.w << 16);
  a[7] += __uint_as_float(u.w & 0xffff0000u);
}

// ---------------- prep: atomic degree hist | x->bf16 | W^T x3 | zero rows ----
__global__ __launch_bounds__(1024) void prep_kernel(
    const float* __restrict__ x, const float* __restrict__ W1,
    const float* __restrict__ W2, const float* __restrict__ W3,
    const int* __restrict__ src, const int* __restrict__ dst,
    unsigned short* __restrict__ h0, unsigned short* __restrict__ h1,
    unsigned short* __restrict__ T1, unsigned short* __restrict__ T2,
    unsigned short* __restrict__ T3, int* __restrict__ deg_in,
    int* __restrict__ deg_out) {
  int b = blockIdx.x;
  int tid = threadIdx.x;
  if (b < HISTB) {
    int i = b * 1024 + tid;
    if (i < NE) {
      atomicAdd(&deg_in[dst[i]], 1);
      atomicAdd(&deg_out[src[i]], 1);
    }
  } else if (b < HISTB + CVT_BLOCKS) {
    int i = (b - HISTB) * 1024 + tid;
    if (i < NN * D / 4) {
      float4 v = ((const float4*)x)[i];
      uint2 p;
      p.x = packbf(v.x, v.y);
      p.y = packbf(v.z, v.w);
      ((uint2*)h0)[i] = p;
    }
  } else if (b < HISTB + CVT_BLOCKS + WT_BLOCKS) {
    int g = b - (HISTB + CVT_BLOCKS);
    int w = g >> 4;
    int i = (g & 15) * 1024 + tid;  // 0..16383
    const float* W = (w == 0) ? W1 : (w == 1) ? W2 : W3;
    unsigned short* T = (w == 0) ? T1 : (w == 1) ? T2 : T3;
    int n = i >> 7, k = i & 127;
    T[n * 128 + k] = (unsigned short)bf16rne(W[k * 128 + n]);
  } else {
    if (tid < 16) {
      ((uint4*)(h0 + (size_t)NN * D))[tid] = make_uint4(0, 0, 0, 0);
      ((uint4*)(h1 + (size_t)NN * D))[tid] = make_uint4(0, 0, 0, 0);
    }
  }
}

// ---------------- scan of padded (ceil4) degrees ----------------
__device__ __forceinline__ int block_excl_scan(int v, int* wsum) {
  int lane = threadIdx.x & 63;
  int w = threadIdx.x >> 6;
  int incl = v;
#pragma unroll
  for (int off = 1; off < 64; off <<= 1) {
    int t = __shfl_up(incl, off);
    if (lane >= off) incl += t;
  }
  if (lane == 63) wsum[w] = incl;
  __syncthreads();
  int wo = 0;
#pragma unroll
  for (int j = 0; j < 4; ++j)
    if (j < w) wo += wsum[j];
  return wo + incl - v;
}

// block-LOCAL exclusive scan; consumers add partials[node>>8]
__global__ __launch_bounds__(256) void degscan_kernel(const int* __restrict__ deg_in,
                                                      int* __restrict__ row_ptr,
                                                      int* __restrict__ partials, int N) {
  __shared__ int wsum[4];
  int d = blockIdx.x * 256 + threadIdx.x;
  int run = (d < N) ? deg_in[d] : 0;
  int pad = (run + 3) & ~3;
  int excl = block_excl_scan(pad, wsum);
  if (d <= N) row_ptr[d] = excl;
  if (threadIdx.x == 255) partials[blockIdx.x] = excl + pad;
}

__global__ __launch_bounds__(256) void scan2(int* __restrict__ partials, int nb) {
  __shared__ int wsum[4];
  int v = (threadIdx.x < nb) ? partials[threadIdx.x] : 0;
  int excl = block_excl_scan(v, wsum);
  if (threadIdx.x < nb) partials[threadIdx.x] = excl;
}

// cur[i] = row start; write NN-dummy pad tail (disjoint from data slots)
__global__ __launch_bounds__(256) void curpad_kernel(const int* __restrict__ row_ptr,
                                                     const int* __restrict__ partials,
                                                     const int* __restrict__ deg_in,
                                                     int* __restrict__ cur,
                                                     int* __restrict__ csr_src, int N) {
  int i = blockIdx.x * 256 + threadIdx.x;
  if (i >= N) return;
  int st = row_ptr[i] + partials[i >> 8];
  int en = row_ptr[i + 1] + partials[(i + 1) >> 8];
  cur[i] = st;
  int deg = deg_in[i];
  for (int j = st + deg; j < en; ++j) csr_src[j] = NN;
}

// scatter fill via global atomics (within-row order nondeterministic; only
// permutes a ~16-term f32 summation -> noise far below bf16 quantization)
__global__ __launch_bounds__(1024) void fill_kernel(const int* __restrict__ src,
                                                    const int* __restrict__ dst,
                                                    int* __restrict__ cur,
                                                    int* __restrict__ csr_src) {
  int i = blockIdx.x * 1024 + threadIdx.x;
  if (i < NE) {
    int d = dst[i];
    int pos = atomicAdd(&cur[d], 1);
    csr_src[pos] = src[i];
  }
}

// ---------------- fused layer: gather-aggregate (LDS) + MFMA GEMM -----------
// Block = 256 thr = 4 waves, 64 nodes. Phase 1: 16 quarter-waves aggregate 4
// nodes each into sA (bf16, 136-padded rows). Phase 2: the proven mgemm tile
// reads A-fragments from sA instead of global. Ping-pong tables avoid the
// in-place gather/write race. MODE_AGG 0: sage (self + /(deg+1)); 1: *norm_in.
// MODE_SCALE 1: epilogue * rsqrt(max(deg_out,1)). OUT_BF: bf16 table vs f32.
template <int MODE_AGG, int MODE_SCALE, int OUT_BF>
__global__ __launch_bounds__(256) void fused_kernel(
    const unsigned short* __restrict__ tin, const int* __restrict__ row_ptr,
    const int* __restrict__ partials, const int* __restrict__ csr_src,
    const int* __restrict__ deg_in, const int* __restrict__ deg_out,
    const unsigned short* __restrict__ WT, const float* __restrict__ bias,
    unsigned short* __restrict__ outb, float* __restrict__ outf, int N) {
  __shared__ unsigned short sWT[128 * 136];
  __shared__ unsigned short sA[64 * 136];
  int tid = threadIdx.x;
  for (int g = tid; g < 2048; g += 256) {
    int n = g >> 4, c = g & 15;
    uint4 v = ((const uint4*)WT)[g];
    *(uint4*)&sWT[n * 136 + c * 8] = v;
  }
  int qw = tid >> 4;   // 0..15: quarter-wave
  int col = tid & 15;  // 16B granule within row
  int nb = blockIdx.x * 64;
#pragma unroll 1
  for (int s = 0; s < 4; ++s) {
    int nl = qw * 4 + s;  // local node 0..63
    int node = nb + nl;
    float a0[8] = {0, 0, 0, 0, 0, 0, 0, 0};
    float a1[8] = {0, 0, 0, 0, 0, 0, 0, 0};
    if (node < N) {
      int start = row_ptr[node] + partials[node >> 8];
      int end = row_ptr[node + 1] + partials[(node + 1) >> 8];
      int indeg = deg_in[node];
      uint4 srow = make_uint4(0, 0, 0, 0);
      if (MODE_AGG == 0) srow = ((const uint4*)(tin + (size_t)node * D))[col];
      const int* ce = csr_src + start;
      int cnt = end - start;  // multiple of 4
      for (int it = 0; it < cnt; it += 4) {
        int4 ix = *(const int4*)(ce + it);
        uint4 u0 = ((const uint4*)(tin + (size_t)ix.x * D))[col];
        uint4 u1 = ((const uint4*)(tin + (size_t)ix.y * D))[col];
        uint4 u2 = ((const uint4*)(tin + (size_t)ix.z * D))[col];
        uint4 u3 = ((const uint4*)(tin + (size_t)ix.w * D))[col];
        bacc(a0, u0);
        bacc(a1, u1);
        bacc(a0, u2);
        bacc(a1, u3);
      }
#pragma unroll
      for (int j = 0; j < 8; ++j) a0[j] += a1[j];
      if (MODE_AGG == 0) {
        float sf[8] = {0, 0, 0, 0, 0, 0, 0, 0};
        bacc(sf, srow);
        float inv = 1.0f / (float)(indeg + 1);
#pragma unroll
        for (int j = 0; j < 8; ++j) a0[j] = (a0[j] + sf[j]) * inv;
      } else {
        float sc = rsqrtf(fmaxf((float)indeg, 1.0f));
#pragma unroll
        for (int j = 0; j < 8; ++j) a0[j] *= sc;
      }
    }
    uint4 p;
    p.x = packbf(a0[0], a0[1]);
    p.y = packbf(a0[2], a0[3]);
    p.z = packbf(a0[4], a0[5]);
    p.w = packbf(a0[6], a0[7]);
    *(uint4*)&sA[nl * 136 + col * 8] = p;
  }
  __syncthreads();
  // ---- GEMM phase (identical to the verified mgemm, A from LDS) ----
  int wv = tid >> 6;
  int lane = tid & 63;
  int q = lane >> 4;
  int ln = lane & 15;
  const unsigned short* Ar = &sA[(wv * 16 + ln) * 136 + q * 8];
  bf16x8 af0 = *(const bf16x8*)(Ar + 0);
  bf16x8 af1 = *(const bf16x8*)(Ar + 32);
  bf16x8 af2 = *(const bf16x8*)(Ar + 64);
  bf16x8 af3 = *(const bf16x8*)(Ar + 96);
  f32x4 acc[8];
#pragma unroll
  for (int t = 0; t < 8; ++t) acc[t] = (f32x4){0.f, 0.f, 0.f, 0.f};
#pragma unroll
  for (int t = 0; t < 8; ++t) {
    const unsigned short* Wr = &sWT[(t * 16 + ln) * 136 + q * 8];
    bf16x8 b0 = *(const bf16x8*)(Wr + 0);
    bf16x8 b1 = *(const bf16x8*)(Wr + 32);
    bf16x8 b2 = *(const bf16x8*)(Wr + 64);
    bf16x8 b3 = *(const bf16x8*)(Wr + 96);
    acc[t] = __builtin_amdgcn_mfma_f32_16x16x32_bf16(af0, b0, acc[t], 0, 0, 0);
    acc[t] = __builtin_amdgcn_mfma_f32_16x16x32_bf16(af1, b1, acc[t], 0, 0, 0);
    acc[t] = __builtin_amdgcn_mfma_f32_16x16x32_bf16(af2, b2, acc[t], 0, 0, 0);
    acc[t] = __builtin_amdgcn_mfma_f32_16x16x32_bf16(af3, b3, acc[t], 0, 0, 0);
  }
  float scl[4];
#pragma unroll
  for (int r = 0; r < 4; ++r) {
    scl[r] = 1.0f;
    if (MODE_SCALE == 1) {
      int row = nb + wv * 16 + q * 4 + r;
      int rr = (row < N) ? row : 0;
      scl[r] = rsqrtf(fmaxf((float)deg_out[rr], 1.0f));
    }
  }
#pragma unroll
  for (int t = 0; t < 8; ++t) {
    float b = bias[t * 16 + ln];
#pragma unroll
    for (int r = 0; r < 4; ++r) {
      int row = nb + wv * 16 + q * 4 + r;
      if (row < N) {
        float v = (acc[t][r] + b) * scl[r];
        if (OUT_BF)
          outb[(size_t)row * 128 + t * 16 + ln] = (unsigned short)bf16rne(v);
        else
          outf[(size_t)row * 128 + t * 16 + ln] = v;
      }
    }
  }
}

// ---------------- launcher ----------------

extern "C" void kernel_launch(void* const* d_in, const int* in_sizes, int n_in,
                              void* d_out, int out_size, void* d_ws, size_t ws_size,
                              hipStream_t stream) {
  const float* x = (const float*)d_in[0];
  const float* W1 = (const float*)d_in[1];
  const float* b1 = (const float*)d_in[2];
  const float* W2 = (const float*)d_in[3];
  const float* b2 = (const float*)d_in[4];
  const float* W3 = (const float*)d_in[5];
  const float* b3 = (const float*)d_in[6];
  const int* src = (const int*)d_in[7];
  const int* dst = (const int*)d_in[8];
  float* out = (float*)d_out;

  const int N = NN;

  // workspace layout (~30 MB); csr_src offset kept 16B-aligned
  unsigned short* h0 = (unsigned short*)d_ws;          // (NN+1)*D bf16
  unsigned short* h1 = h0 + (size_t)(NN + 1) * D;      // (NN+1)*D bf16
  unsigned short* WT1 = h1 + (size_t)(NN + 1) * D;     // 128*128 bf16
  unsigned short* WT2 = WT1 + D * D;
  unsigned short* WT3 = WT2 + D * D;
  int* deg_in = (int*)(WT3 + D * D);                   // NN
  int* deg_out = deg_in + NN;                          // NN
  int* row_ptr = deg_out + NN;                         // NN+1 (alloc NN+4)
  int* partials = row_ptr + NN + 4;                    // 256
  int* cur = partials + 256;                           // NN
  int* csr_src = cur + NN;                             // CSRCAP

  const int scanBlocks = (N + 255) / 256;  // 196

  hipMemsetAsync(deg_in, 0, 2 * (size_t)NN * sizeof(int), stream);
  prep_kernel<<<HISTB + CVT_BLOCKS + WT_BLOCKS + 1, 1024, 0, stream>>>(
      x, W1, W2, W3, src, dst, h0, h1, WT1, WT2, WT3, deg_in, deg_out);
  degscan_kernel<<<scanBlocks, 256, 0, stream>>>(deg_in, row_ptr, partials, N);
  scan2<<<1, 256, 0, stream>>>(partials, scanBlocks);
  curpad_kernel<<<scanBlocks, 256, 0, stream>>>(row_ptr, partials, deg_in, cur,
                                                csr_src, N);
  fill_kernel<<<HISTB, 1024, 0, stream>>>(src, dst, cur, csr_src);

  int layerBlocks = (N + 63) / 64;  // 782

  // layer 1: sage(x): h0 -> h1
  fused_kernel<0, 0, 1><<<layerBlocks, 256, 0, stream>>>(
      h0, row_ptr, partials, csr_src, deg_in, deg_out, WT1, b1, h1, nullptr, N);
  // layer 2: sage(h1) with norm_out folded into epilogue: h1 -> h0
  fused_kernel<0, 1, 1><<<layerBlocks, 256, 0, stream>>>(
      h1, row_ptr, partials, csr_src, deg_in, deg_out, WT2, b2, h0, nullptr, N);
  // layer 3: gcn: (agg(h0) * norm_in) @ W3 + b3 -> out (f32)
  fused_kernel<1, 0, 0><<<layerBlocks, 256, 0, stream>>>(
      h0, row_ptr, partials, csr_src, deg_in, deg_out, WT3, b3, nullptr, out, N);
}

// Round 5
// 268.698 us; speedup vs baseline: 1.3800x; 1.3800x over previous
//
#include <hip/hip_runtime.h>

#define NN 50000
#define NE 800000
#define D 128

#define CH 32              // edge chunks
#define EPC (NE / CH)      // 25000 edges per chunk
#define RGH 4              // node ranges (160KB LDS lets us halve the passes)
#define NPRH (NN / RGH)    // 12500 nodes per range
#define CSRCAP (NE + 8 * NN)

#define HIST_BLOCKS (CH * RGH)  // 128
#define CVT_BLOCKS 1563         // ceil(1.6M / 1024)
#define WT_BLOCKS 48            // 3 matrices x 16384 / 1024

typedef short bf16x8 __attribute__((ext_vector_type(8)));
typedef float f32x4 __attribute__((ext_vector_type(4)));

// ---------------- bf16 helpers ----------------

__device__ __forceinline__ unsigned bf16rne(float f) {
  unsigned u = __float_as_uint(f);
  return (u + 0x7fffu + ((u >> 16) & 1u)) >> 16;
}
__device__ __forceinline__ unsigned packbf(float lo, float hi) {
  return bf16rne(lo) | (bf16rne(hi) << 16);
}

// fused: hist (blocks 0..127) | x->bf16 | W^T bf16 x3 | zero row NN
__global__ __launch_bounds__(1024) void cvtw_hist_kernel(
    const float* __restrict__ x, const float* __restrict__ W1,
    const float* __restrict__ W2, const float* __restrict__ W3,
    unsigned short* __restrict__ hbf, unsigned short* __restrict__ T1,
    unsigned short* __restrict__ T2, unsigned short* __restrict__ T3,
    const int* __restrict__ src, const int* __restrict__ dst,
    int* __restrict__ partial_dst, int* __restrict__ partial_src) {
  __shared__ int hd[NPRH];
  __shared__ int hs[NPRH];
  int b = blockIdx.x;
  int tid = threadIdx.x;
  if (b < HIST_BLOCKS) {
    int c = b >> 2;
    int r = b & 3;
    int base = r * NPRH;
    for (int i = tid; i < NPRH; i += 1024) { hd[i] = 0; hs[i] = 0; }
    __syncthreads();
    int e0 = c * EPC;
    for (int i = tid; i < EPC; i += 1024) {
      int d = dst[e0 + i];
      int s = src[e0 + i];
      unsigned dr = (unsigned)(d - base);
      unsigned sr = (unsigned)(s - base);
      if (dr < NPRH) atomicAdd(&hd[dr], 1);
      if (sr < NPRH) atomicAdd(&hs[sr], 1);
    }
    __syncthreads();
    for (int i = tid; i < NPRH; i += 1024) {
      partial_dst[c * NN + base + i] = hd[i];
      partial_src[c * NN + base + i] = hs[i];
    }
  } else if (b < HIST_BLOCKS + CVT_BLOCKS) {
    int i = (b - HIST_BLOCKS) * 1024 + tid;
    if (i < NN * D / 4) {
      float4 v = ((const float4*)x)[i];
      uint2 p;
      p.x = packbf(v.x, v.y);
      p.y = packbf(v.z, v.w);
      ((uint2*)hbf)[i] = p;
    }
  } else if (b < HIST_BLOCKS + CVT_BLOCKS + WT_BLOCKS) {
    int g = b - (HIST_BLOCKS + CVT_BLOCKS);
    int w = g >> 4;
    int i = (g & 15) * 1024 + tid;  // 0..16383
    const float* W = (w == 0) ? W1 : (w == 1) ? W2 : W3;
    unsigned short* T = (w == 0) ? T1 : (w == 1) ? T2 : T3;
    int n = i >> 7, k = i & 127;
    T[n * 128 + k] = (unsigned short)bf16rne(W[k * 128 + n]);
  } else {
    if (tid < 16) ((uint4*)(hbf + (size_t)NN * D))[tid] = make_uint4(0, 0, 0, 0);
  }
}

__device__ __forceinline__ int block_excl_scan(int v, int* wsum) {
  int lane = threadIdx.x & 63;
  int w = threadIdx.x >> 6;
  int incl = v;
#pragma unroll
  for (int off = 1; off < 64; off <<= 1) {
    int t = __shfl_up(incl, off);
    if (lane >= off) incl += t;
  }
  if (lane == 63) wsum[w] = incl;
  __syncthreads();
  int wo = 0;
#pragma unroll
  for (int j = 0; j < 4; ++j)
    if (j < w) wo += wsum[j];
  return wo + incl - v;
}

// fused reduce + scan phase 1: chunk-prefix partial_dst in place, true in-deg
// -> degtmp, out-deg -> deg_out, block-LOCAL exclusive scan of PADDED degree
// (ceil8) -> row_ptr, block totals -> partials. Consumers add partials[n>>8];
// no scan3 pass needed.
__global__ __launch_bounds__(256) void degscan_kernel(int* __restrict__ partial_dst,
                                                      const int* __restrict__ partial_src,
                                                      int* __restrict__ degtmp,
                                                      int* __restrict__ deg_out,
                                                      int* __restrict__ row_ptr,
                                                      int* __restrict__ partials, int N) {
  __shared__ int wsum[4];
  int d = blockIdx.x * 256 + threadIdx.x;
  int run = 0;
  if (d < N) {
#pragma unroll
    for (int c = 0; c < CH; ++c) {
      int v = partial_dst[c * NN + d];
      partial_dst[c * NN + d] = run;
      run += v;
    }
    degtmp[d] = run;
    int ro = 0;
#pragma unroll
    for (int c = 0; c < CH; ++c) ro += partial_src[c * NN + d];
    deg_out[d] = ro;
  }
  int pad = (run + 7) & ~7;  // pad rows to x8 for the 8-edge gather loop
  int excl = block_excl_scan(pad, wsum);
  if (d <= N) row_ptr[d] = excl;  // d==N gets local end-of-block-195 prefix
  if (threadIdx.x == 255) partials[blockIdx.x] = excl + pad;
}

__global__ __launch_bounds__(256) void scan2(int* __restrict__ partials, int nb) {
  __shared__ int wsum[4];
  int v = (threadIdx.x < nb) ? partials[threadIdx.x] : 0;
  int excl = block_excl_scan(v, wsum);
  if (threadIdx.x < nb) partials[threadIdx.x] = excl;
}

// scatter fill; the last-chunk block also writes the NN-dummy pad tails
// (pad slots are disjoint from data slots, and this block's cur[] ends at
// row_start + deg exactly, so no inter-block ordering is needed).
__global__ __launch_bounds__(1024) void fill_kernel(const int* __restrict__ src,
                                                    const int* __restrict__ dst,
                                                    const int* __restrict__ row_ptr,
                                                    const int* __restrict__ partials,
                                                    const int* __restrict__ partial_dst,
                                                    int* __restrict__ csr_src) {
  __shared__ int cur[NPRH];
  int tid = threadIdx.x;
  int c = blockIdx.x >> 2;
  int r = blockIdx.x & 3;
  int base = r * NPRH;
  for (int i = tid; i < NPRH; i += 1024) {
    int nd = base + i;
    cur[i] = row_ptr[nd] + partials[nd >> 8] + partial_dst[c * NN + nd];
  }
  __syncthreads();
  int e0 = c * EPC;
  for (int i = tid; i < EPC; i += 1024) {
    int d = dst[e0 + i];
    unsigned dr = (unsigned)(d - base);
    if (dr < NPRH) {
      int pos = atomicAdd(&cur[dr], 1);
      csr_src[pos] = src[e0 + i];
    }
  }
  if (c == CH - 1) {
    __syncthreads();
    for (int i = tid; i < NPRH; i += 1024) {
      int nd = base + i;
      int s = cur[i];  // == global row start + deg
      int e = row_ptr[nd + 1] + partials[(nd + 1) >> 8];
      for (int j = s; j < e; ++j) csr_src[j] = NN;
    }
  }
}

// ---------------- aggregation: one QUARTER-WAVE (16 lanes) per node ---------
// Each lane owns 8 channels of one node; edges consumed 8 at a time via two
// int4 index loads -> 32 row-loads in flight per wave (2x round 3's MLP).
// Rows padded to x8 with dummy index NN (zero row, L1-resident).
// bf16 in, f32 accumulate, bf16 out. MODE 0: sage. MODE 1: gcn rsqrt.
__device__ __forceinline__ void bacc(float* a, uint4 u) {
  a[0] += __uint_as_float(u.x << 16);
  a[1] += __uint_as_float(u.x & 0xffff0000u);
  a[2] += __uint_as_float(u.y << 16);
  a[3] += __uint_as_float(u.y & 0xffff0000u);
  a[4] += __uint_as_float(u.z << 16);
  a[5] += __uint_as_float(u.z & 0xffff0000u);
  a[6] += __uint_as_float(u.w << 16);
  a[7] += __uint_as_float(u.w & 0xffff0000u);
}

template <int MODE>
__global__ __launch_bounds__(256, 4) void agg_kernel(const unsigned short* __restrict__ hb,
                                                     const int* __restrict__ row_ptr,
                                                     const int* __restrict__ partials,
                                                     const int* __restrict__ csr_src,
                                                     const int* __restrict__ degtmp,
                                                     unsigned short* __restrict__ outb, int N) {
  int qw = threadIdx.x >> 4;   // 0..15: quarter-wave = node slot
  int col = threadIdx.x & 15;  // 16B granule within row
  int node = blockIdx.x * 16 + qw;
  if (node >= N) return;
  int start = row_ptr[node] + partials[node >> 8];
  int end = row_ptr[node + 1] + partials[(node + 1) >> 8];
  int indeg = degtmp[node];
  uint4 srow = make_uint4(0, 0, 0, 0);
  if (MODE == 0) srow = ((const uint4*)(hb + (size_t)node * D))[col];
  float a0[8] = {0, 0, 0, 0, 0, 0, 0, 0};
  float a1[8] = {0, 0, 0, 0, 0, 0, 0, 0};
  const int* ce = csr_src + start;
  int cnt = end - start;  // multiple of 8
  for (int it = 0; it < cnt; it += 8) {
    int4 ia = *(const int4*)(ce + it);
    int4 ib = *(const int4*)(ce + it + 4);
    uint4 u0 = ((const uint4*)(hb + (size_t)ia.x * D))[col];
    uint4 u1 = ((const uint4*)(hb + (size_t)ia.y * D))[col];
    uint4 u2 = ((const uint4*)(hb + (size_t)ia.z * D))[col];
    uint4 u3 = ((const uint4*)(hb + (size_t)ia.w * D))[col];
    uint4 u4 = ((const uint4*)(hb + (size_t)ib.x * D))[col];
    uint4 u5 = ((const uint4*)(hb + (size_t)ib.y * D))[col];
    uint4 u6 = ((const uint4*)(hb + (size_t)ib.z * D))[col];
    uint4 u7 = ((const uint4*)(hb + (size_t)ib.w * D))[col];
    bacc(a0, u0);
    bacc(a1, u1);
    bacc(a0, u2);
    bacc(a1, u3);
    bacc(a0, u4);
    bacc(a1, u5);
    bacc(a0, u6);
    bacc(a1, u7);
  }
#pragma unroll
  for (int j = 0; j < 8; ++j) a0[j] += a1[j];
  if (MODE == 0) {
    float sf[8] = {0, 0, 0, 0, 0, 0, 0, 0};
    bacc(sf, srow);
    float inv = 1.0f / (float)(indeg + 1);
#pragma unroll
    for (int j = 0; j < 8; ++j) a0[j] = (a0[j] + sf[j]) * inv;
  } else {
    float sc = rsqrtf(fmaxf((float)indeg, 1.0f));
#pragma unroll
    for (int j = 0; j < 8; ++j) a0[j] *= sc;
  }
  uint4 p;
  p.x = packbf(a0[0], a0[1]);
  p.y = packbf(a0[2], a0[3]);
  p.z = packbf(a0[4], a0[5]);
  p.w = packbf(a0[6], a0[7]);
  ((uint4*)(outb + (size_t)node * D))[col] = p;
}

// ---------------- MFMA GEMM: [N x 128](bf16) @ [128 x 128] + bias ------------
// 256 thr = 4 waves; block tile 64 rows; wave tile 16 rows x 128 cols.
// MODE 1: scale rows by rsqrt(max(deg_out,1)). OUT_BF 1: write bf16 table.
template <int MODE, int OUT_BF>
__global__ __launch_bounds__(256) void mgemm_kernel(const unsigned short* __restrict__ A,
                                                    const unsigned short* __restrict__ WT,
                                                    const float* __restrict__ bias,
                                                    const int* __restrict__ deg_out,
                                                    float* __restrict__ outf,
                                                    unsigned short* __restrict__ outb, int N) {
  __shared__ unsigned short sWT[128 * 136];
  int tid = threadIdx.x;
  for (int g = tid; g < 2048; g += 256) {
    int n = g >> 4, c = g & 15;
    uint4 v = ((const uint4*)WT)[g];
    *(uint4*)&sWT[n * 136 + c * 8] = v;
  }
  int wv = tid >> 6;
  int lane = tid & 63;
  int q = lane >> 4;
  int ln = lane & 15;
  int row0 = blockIdx.x * 64 + wv * 16;
  int arow = row0 + ln;
  if (arow >= N) arow = 0;  // clamp; stores are guarded
  const unsigned short* Ar = A + (size_t)arow * 128 + q * 8;
  bf16x8 af0 = *(const bf16x8*)(Ar + 0);
  bf16x8 af1 = *(const bf16x8*)(Ar + 32);
  bf16x8 af2 = *(const bf16x8*)(Ar + 64);
  bf16x8 af3 = *(const bf16x8*)(Ar + 96);
  f32x4 acc[8];
#pragma unroll
  for (int t = 0; t < 8; ++t) acc[t] = (f32x4){0.f, 0.f, 0.f, 0.f};
  __syncthreads();
#pragma unroll
  for (int t = 0; t < 8; ++t) {
    const unsigned short* Wr = &sWT[(t * 16 + ln) * 136 + q * 8];
    bf16x8 b0 = *(const bf16x8*)(Wr + 0);
    bf16x8 b1 = *(const bf16x8*)(Wr + 32);
    bf16x8 b2 = *(const bf16x8*)(Wr + 64);
    bf16x8 b3 = *(const bf16x8*)(Wr + 96);
    acc[t] = __builtin_amdgcn_mfma_f32_16x16x32_bf16(af0, b0, acc[t], 0, 0, 0);
    acc[t] = __builtin_amdgcn_mfma_f32_16x16x32_bf16(af1, b1, acc[t], 0, 0, 0);
    acc[t] = __builtin_amdgcn_mfma_f32_16x16x32_bf16(af2, b2, acc[t], 0, 0, 0);
    acc[t] = __builtin_amdgcn_mfma_f32_16x16x32_bf16(af3, b3, acc[t], 0, 0, 0);
  }
  float scl[4];
#pragma unroll
  for (int r = 0; r < 4; ++r) {
    scl[r] = 1.0f;
    if (MODE == 1) {
      int row = row0 + q * 4 + r;
      int rr = (row < N) ? row : 0;
      scl[r] = rsqrtf(fmaxf((float)deg_out[rr], 1.0f));
    }
  }
#pragma unroll
  for (int t = 0; t < 8; ++t) {
    float b = bias[t * 16 + ln];
#pragma unroll
    for (int r = 0; r < 4; ++r) {
      int row = row0 + q * 4 + r;
      if (row < N) {
        float v = (acc[t][r] + b) * scl[r];
        if (OUT_BF)
          outb[(size_t)row * 128 + t * 16 + ln] = (unsigned short)bf16rne(v);
        else
          outf[(size_t)row * 128 + t * 16 + ln] = v;
      }
    }
  }
}

// ---------------- launcher ----------------

extern "C" void kernel_launch(void* const* d_in, const int* in_sizes, int n_in,
                              void* d_out, int out_size, void* d_ws, size_t ws_size,
                              hipStream_t stream) {
  const float* x = (const float*)d_in[0];
  const float* W1 = (const float*)d_in[1];
  const float* b1 = (const float*)d_in[2];
  const float* W2 = (const float*)d_in[3];
  const float* b2 = (const float*)d_in[4];
  const float* W3 = (const float*)d_in[5];
  const float* b3 = (const float*)d_in[6];
  const int* src = (const int*)d_in[7];
  const int* dst = (const int*)d_in[8];
  float* out = (float*)d_out;

  const int N = NN;

  // workspace layout (~46 MB)
  unsigned short* hbf = (unsigned short*)d_ws;             // (NN+1)*D bf16
  unsigned short* aggB = hbf + (size_t)(NN + 1) * D;       // NN*D bf16
  unsigned short* WT1 = aggB + (size_t)NN * D;             // 128*128 bf16
  unsigned short* WT2 = WT1 + D * D;
  unsigned short* WT3 = WT2 + D * D;
  int* partial_dst = (int*)(WT3 + D * D);                  // CH*NN
  int* partial_src = partial_dst + (size_t)CH * NN;        // CH*NN
  int* degtmp = partial_src + (size_t)CH * NN;             // NN
  int* deg_out = degtmp + NN;                              // NN
  int* row_ptr = deg_out + NN;                             // NN+1 (alloc NN+4)
  int* partials = row_ptr + NN + 4;                        // 256
  int* csr_src = partials + 256;                           // CSRCAP

  const int scanBlocks = (N + 255) / 256;  // 196

  cvtw_hist_kernel<<<HIST_BLOCKS + CVT_BLOCKS + WT_BLOCKS + 1, 1024, 0, stream>>>(
      x, W1, W2, W3, hbf, WT1, WT2, WT3, src, dst, partial_dst, partial_src);
  degscan_kernel<<<scanBlocks, 256, 0, stream>>>(partial_dst, partial_src, degtmp,
                                                 deg_out, row_ptr, partials, N);
  scan2<<<1, 256, 0, stream>>>(partials, scanBlocks);
  fill_kernel<<<CH * RGH, 1024, 0, stream>>>(src, dst, row_ptr, partials, partial_dst,
                                             csr_src);

  int aggBlocks = (N + 15) / 16;  // 3125
  int gemmBlocks = (N + 63) / 64;

  // layer 1: sage(x)
  agg_kernel<0><<<aggBlocks, 256, 0, stream>>>(hbf, row_ptr, partials, csr_src, degtmp,
                                               aggB, N);
  mgemm_kernel<0, 1><<<gemmBlocks, 256, 0, stream>>>(aggB, WT1, b1, deg_out, nullptr, hbf, N);
  // layer 2: sage(h1); fold norm_out for layer 3 into epilogue
  agg_kernel<0><<<aggBlocks, 256, 0, stream>>>(hbf, row_ptr, partials, csr_src, degtmp,
                                               aggB, N);
  mgemm_kernel<1, 1><<<gemmBlocks, 256, 0, stream>>>(aggB, WT2, b2, deg_out, nullptr, hbf, N);
  // layer 3: gcn: (agg(h2*norm_out) * norm_in) @ W3 + b3
  agg_kernel<1><<<aggBlocks, 256, 0, stream>>>(hbf, row_ptr, partials, csr_src, degtmp,
                                               aggB, N);
  mgemm_kernel<0, 0><<<gemmBlocks, 256, 0, stream>>>(aggB, WT3, b3, deg_out, out, nullptr, N);
}